// Round 14
// baseline (237.577 us; speedup 1.0000x reference)
//
#include <hip/hip_runtime.h>
#include <math.h>

#define BATCH 16
#define SEQLEN 4096
#define D_MODEL 96
#define D_STATE 6
#define D_CONV 9
#define D_INNER 192
#define DT_RANK 6
#define NPOS (BATCH * SEQLEN)

#define NC2 128            // chunks per sequence
#define CT2 (SEQLEN / NC2) // 32 steps per chunk
#define NSEG 16            // level-2 segments
#define CPS (NC2 / NSEG)   // chunks per segment = 8

// workspace layout (in floats). xs/z no longer exist in HBM (fused into A).
#define OFF_OUT4  0L                                          // B*NC2*5*192 float4s
#define OFF_SEG   (OFF_OUT4 + (long)BATCH * NC2 * 5 * 192 * 4)
#define OFF_XPART (OFF_SEG  + (long)BATCH * NSEG * 5 * 192 * 4) // B*NC2*96 xbar partials

typedef short v8s __attribute__((ext_vector_type(8)));   // 8 x bf16 (MFMA A/B frag)
typedef float v4f __attribute__((ext_vector_type(4)));   // MFMA C/D frag

__device__ __forceinline__ float silu_fast(float v) {
    return __fdividef(v, 1.0f + __expf(-v));
}
__device__ __forceinline__ float softplus_fast(float v) {
    return (v > 20.0f) ? v : __logf(1.0f + __expf(v));
}
__device__ __forceinline__ float eluf(float v) {
    return (v > 0.0f) ? v : expm1f(v);
}
__device__ __forceinline__ unsigned int pack_bf16(float a, float b) {
    unsigned int ua = __float_as_uint(a), ub = __float_as_uint(b);
    ua += 0x7FFFu + ((ua >> 16) & 1u);
    ub += 0x7FFFu + ((ub >> 16) & 1u);
    return (ua >> 16) | (ub & 0xFFFF0000u);
}
__device__ __forceinline__ unsigned short bf16h(float v) {
    unsigned int u = __float_as_uint(v);
    u += 0x7FFFu + ((u >> 16) & 1u);
    return (unsigned short)(u >> 16);
}
__device__ __forceinline__ float bf2f(unsigned short h) {
    return __uint_as_float(((unsigned int)h) << 16);
}

// ---------------------------------------------------------------------------
// KA (fused): per (b,c) chunk block of 192 threads:
//   1. stage x rows l0-8..l0+31 (40 pos, zero-pad l<0) -> hRow fp32
//   2. rmsnorm scales + xbar partial (owned 32 positions) -> xpart
//   3. normalize+pack -> hN bf16
//   4. in_proj via MFMA: xz[40][384] computed in 6 stages (3 K-chunks x 2
//      halves), D(row=pos, col=j) -> sxs (xs, 40 rows) / zL (z, 32 rows) bf16
//   5. conv(9)+silu in-LDS (column-local, overwrites dead xs rows with xc)
//   6. dbc GEMM via MFMA -> sMeta
//   7. chunk scan (G-trick, power-chain exp) -> out4 planes
// LDS 54.1 KB (hRow/WB/sxpB union; hN/sMeta union) -> 3 blocks/CU.
// Halo (8 pos) recomputed redundantly — 25% extra MFMA in a 0.5%-MfmaUtil
// kernel. Removes k1 dispatch + 75 MB xs/z HBM round-trip entirely.
// ---------------------------------------------------------------------------
#define SXSTR 200   // ushort stride; 100 dw %32=4 -> bank spread; rows 16B-aligned
__global__ __launch_bounds__(192, 2) void ka_fused(
    const float* __restrict__ x, const float* __restrict__ W,
    const float* __restrict__ norm_w,
    const float* __restrict__ conv_w, const float* __restrict__ conv_b,
    const float* __restrict__ x_proj_w,
    const float* __restrict__ dt_w, const float* __restrict__ dt_b,
    const float* __restrict__ A_log, const float* __restrict__ D_param,
    float4* __restrict__ out4, float* __restrict__ xpart)
{
    __shared__ unsigned short sxs[40 * SXSTR];  // 16.0 KB xs rows p=0..39; rows 0..31 become xc
    __shared__ unsigned short zL[32 * SXSTR];   // 12.8 KB z rows (pos l0..l0+31)
    __shared__ unsigned int   s_wb[4040];       // 16.2 KB union: hRow fp32[40*101] / WB uint[192*20] / sxpB ushort[18*200]
    __shared__ unsigned int   s_hN[40 * 52];    // 8.3 KB union: hN bf16 pairs / sMeta fp32[32][20]
    __shared__ float s_scale[40];
    __shared__ float s_part[40][4];

    float* hRow = (float*)s_wb;                 // [p][d] stride 101
    unsigned int* WB = s_wb;                    // [j][kpair] stride 20 dw
    unsigned short* sxpB = (unsigned short*)s_wb; // [f][k] stride SXSTR
    float* sMeta = (float*)s_hN;                // [t][20]

    const int tid = threadIdx.x;
    const int c = blockIdx.x & (NC2 - 1);
    const int b = blockIdx.x >> 7;
    const int l0 = c * CT2;
    const long brow = (long)b * SEQLEN;

    // ---- 1. stage x (40 rows x 96) as float4; zero rows with l<0 ----
    {
        const float4* x4 = (const float4*)&x[0];
        long gbase = (brow + l0 - 8) * 24;      // float4 index of row p=0
        for (int i = tid; i < 40 * 24; i += 192) {
            int p = i / 24, dq = i - p * 24;
            float4 v = {0.f, 0.f, 0.f, 0.f};
            if (l0 - 8 + p >= 0) v = x4[gbase + i];
            float* hr = &hRow[p * 101 + dq * 4];
            hr[0] = v.x; hr[1] = v.y; hr[2] = v.z; hr[3] = v.w;
        }
    }
    __syncthreads();

    // ---- 2. rms partials ----
    if (tid < 160) {
        int p = tid >> 2, g = tid & 3;
        float ss = 0.0f;
        for (int d = g; d < 96; d += 4) { float v = hRow[p * 101 + d]; ss += v * v; }
        s_part[p][g] = ss;
    }
    __syncthreads();
    if (tid < 40) {
        float ss = s_part[tid][0] + s_part[tid][1] + s_part[tid][2] + s_part[tid][3];
        s_scale[tid] = 1.0f / sqrtf(ss / 96.0f + 1e-5f);
    } else if (tid < 40 + 96) {
        // xbar partial over the 32 OWNED positions (p = 8..39), raw x
        int d = tid - 40;
        float s = 0.0f;
        for (int p = 8; p < 40; p++) s += hRow[p * 101 + d];
        xpart[(long)(b * NC2 + c) * 96 + d] = s;
    }
    __syncthreads();

    // ---- 3. normalize + pack -> hN ----
    {
        const float2* nw2 = (const float2*)norm_w;
        for (int i = tid; i < 40 * 48; i += 192) {
            int p = i / 48, dp = i - p * 48;
            float sc = s_scale[p];
            float2 nv = nw2[dp];
            float v0 = hRow[p * 101 + 2 * dp]     * sc * nv.x;
            float v1 = hRow[p * 101 + 2 * dp + 1] * sc * nv.y;
            s_hN[p * 52 + dp] = pack_bf16(v0, v1);
        }
    }

    const int wave = tid >> 6, lane = tid & 63;
    const int quad = lane >> 4, ln = lane & 15;

    // ---- 4. in_proj MFMA: D(row=pos from h, col=j from W) ----
    v4f accX[3][4], accZ[3][4];
#pragma unroll
    for (int mt = 0; mt < 3; mt++)
#pragma unroll
        for (int nt = 0; nt < 4; nt++) {
            accX[mt][nt] = (v4f){0.f, 0.f, 0.f, 0.f};
            accZ[mt][nt] = (v4f){0.f, 0.f, 0.f, 0.f};
        }

    for (int kc = 0; kc < 3; kc++) {
#pragma unroll
        for (int half = 0; half < 2; half++) {
            __syncthreads();   // WB readers done (1st iter: hRow readers done)
            for (int i = tid; i < 192 * 16; i += 192) {
                int j = i >> 4, kp = i & 15;
                const float2 wv = *(const float2*)&W[(half * 192 + j) * 96 + kc * 32 + 2 * kp];
                WB[j * 20 + kp] = pack_bf16(wv.x, wv.y);
            }
            __syncthreads();

            v8s af[3];
#pragma unroll
            for (int mt = 0; mt < 3; mt++) {
                int pr = mt * 16 + ln;
                if (pr > 39) pr = 39;   // clamp (dup rows, results discarded)
                af[mt] = *(const v8s*)&s_hN[pr * 52 + kc * 16 + quad * 4];
            }
#pragma unroll
            for (int nt = 0; nt < 4; nt++) {
                int jn = wave * 64 + nt * 16 + ln;
                v8s bw = *(const v8s*)&WB[jn * 20 + quad * 4];
                if (half == 0) {
#pragma unroll
                    for (int mt = 0; mt < 3; mt++)
                        accX[mt][nt] = __builtin_amdgcn_mfma_f32_16x16x32_bf16(
                            af[mt], bw, accX[mt][nt], 0, 0, 0);
                } else {
#pragma unroll
                    for (int mt = 0; mt < 3; mt++)
                        accZ[mt][nt] = __builtin_amdgcn_mfma_f32_16x16x32_bf16(
                            af[mt], bw, accZ[mt][nt], 0, 0, 0);
                }
            }
        }
    }

    // epilogue: lane owns col j, rows p = mt*16 + quad*4 + r
#pragma unroll
    for (int mt = 0; mt < 3; mt++) {
#pragma unroll
        for (int nt = 0; nt < 4; nt++) {
            int j = wave * 64 + nt * 16 + ln;
#pragma unroll
            for (int r = 0; r < 4; r++) {
                int p = mt * 16 + quad * 4 + r;
                if (p < 40) {
                    sxs[p * SXSTR + j] = bf16h(accX[mt][nt][r]);
                    if (p >= 8) zL[(p - 8) * SXSTR + j] = bf16h(accZ[mt][nt][r]);
                }
            }
        }
    }
    __syncthreads();

    // ---- 5. stage x_proj_w (into dead WB region) + conv (column-local) ----
    {
        unsigned int* xpB = (unsigned int*)sxpB;
        for (int i = tid; i < 18 * 96; i += 192) {
            int f = i / 96, kp = i - f * 96;
            const float2 wv = *(const float2*)&x_proj_w[f * 192 + 2 * kp];
            xpB[f * (SXSTR / 2) + kp] = pack_bf16(wv.x, wv.y);
        }
    }
    {
        const int e = tid;
        float cw[D_CONV];
#pragma unroll
        for (int k = 0; k < D_CONV; k++) cw[k] = conv_w[e * D_CONV + k];
        const float cb = conv_b[e];
        float win[D_CONV];
#pragma unroll
        for (int k = 0; k < 8; k++) win[k] = bf2f(sxs[k * SXSTR + e]);
#pragma unroll
        for (int r = 0; r < CT2; r++) {
            win[8] = bf2f(sxs[(r + 8) * SXSTR + e]);
            float s = cb;
#pragma unroll
            for (int k = 0; k < D_CONV; k++) s += win[k] * cw[k];
            sxs[r * SXSTR + e] = bf16h(silu_fast(s));   // row r dead as xs
#pragma unroll
            for (int k = 0; k < 8; k++) win[k] = win[k + 1];
        }
    }
    __syncthreads();

    // ---- 6. dbc GEMM via MFMA: D[t][f] = sum_e xc[t][e]*xp[f][e] ----
    if (wave < 2) {
        const int mt = wave;
        const int r1 = (ln < 2) ? 16 + ln : 0;   // clamp: f>=18 cols discarded
        v4f dacc[2];
        dacc[0] = (v4f){0.f, 0.f, 0.f, 0.f};
        dacc[1] = (v4f){0.f, 0.f, 0.f, 0.f};
#pragma unroll
        for (int kc = 0; kc < 6; kc++) {
            v8s af  = *(const v8s*)&sxs[(mt * 16 + ln) * SXSTR + kc * 32 + quad * 8];
            v8s bf0 = *(const v8s*)&sxpB[ln * SXSTR + kc * 32 + quad * 8];
            v8s bf1 = *(const v8s*)&sxpB[r1 * SXSTR + kc * 32 + quad * 8];
            dacc[0] = __builtin_amdgcn_mfma_f32_16x16x32_bf16(af, bf0, dacc[0], 0, 0, 0);
            dacc[1] = __builtin_amdgcn_mfma_f32_16x16x32_bf16(af, bf1, dacc[1], 0, 0, 0);
        }
#pragma unroll
        for (int nt = 0; nt < 2; nt++) {
            int f = nt * 16 + ln;
            if (f < 18) {
                int col = (f < 6) ? f : f + 2;
#pragma unroll
                for (int r = 0; r < 4; r++)
                    sMeta[(mt * 16 + quad * 4 + r) * 20 + col] = dacc[nt][r];
            }
        }
    }
    __syncthreads();

    // ---- 7. chunk scan ----
    const int e = tid;
    float a[D_STATE];
#pragma unroll
    for (int n = 0; n < D_STATE; n++) a[n] = -__expf(A_log[e * D_STATE + n]);
    float dtw[DT_RANK];
#pragma unroll
    for (int q = 0; q < DT_RANK; q++) dtw[q] = dt_w[e * DT_RANK + q];
    const float dtb = dt_b[e];
    const float Dv = D_param[e];
    const float a0 = a[0];

    bool pok = true;
#pragma unroll
    for (int n = 1; n < D_STATE; n++)
        pok = pok && (fabsf(a[n] - (float)(n + 1) * a0)
                      <= 1e-4f * (float)(n + 1) * fabsf(a0));
    unsigned long long pmask = __ballot(pok);

    float S[D_STATE], G[D_STATE];
#pragma unroll
    for (int n = 0; n < D_STATE; n++) { S[n] = 0.0f; G[n] = 0.0f; }
    float ysum0 = 0.0f;

    if (pmask == 0xFFFFFFFFFFFFFFFFull) {
        float Pa = 1.0f;
#pragma unroll 2
        for (int t = 0; t < CT2; t++) {
            const float4* m4 = (const float4*)&sMeta[t * 20];
            float4 m0 = m4[0], m1 = m4[1], mB0 = m4[2], mB1 = m4[3], mC = m4[4];
            float Bv[6] = {mB0.x, mB0.y, mB0.z, mB0.w, mB1.x, mB1.y};
            float Cv[6] = {mB1.z, mB1.w, mC.x, mC.y, mC.z, mC.w};
            float dr = dtb + m0.x * dtw[0] + m0.y * dtw[1] + m0.z * dtw[2]
                     + m0.w * dtw[3] + m1.x * dtw[4] + m1.y * dtw[5];
            float dl = softplus_fast(dr);
            float xv = bf2f(sxs[t * SXSTR + e]);
            float zw = silu_fast(bf2f(zL[t * SXSTR + e]));
            float dx = dl * xv;
            float y = Dv * xv;
            float E = __expf(dl * a0);
            Pa *= E;
            float dA = E, Pn = Pa;
#pragma unroll
            for (int n = 0; n < D_STATE; n++) {
                S[n] = dA * S[n] + dx * Bv[n];
                y += S[n] * Cv[n];
                G[n] += zw * Pn * Cv[n];
                dA *= E;
                Pn *= Pa;
            }
            ysum0 += zw * y;
        }
        long ob = (long)(b * NC2 + c) * 5 * 192 + e;
        float P1 = Pa, P2 = P1 * Pa, P3 = P2 * Pa, P4 = P3 * Pa, P5 = P4 * Pa, P6 = P5 * Pa;
        float4 q0, q1, q2, q3, q4;
        q0.x=P1; q0.y=P2; q0.z=P3; q0.w=P4;
        q1.x=P5; q1.y=P6; q1.z=S[0]; q1.w=S[1];
        q2.x=S[2]; q2.y=S[3]; q2.z=S[4]; q2.w=S[5];
        q3.x=G[0]; q3.y=G[1]; q3.z=G[2]; q3.w=G[3];
        q4.x=G[4]; q4.y=G[5]; q4.z=ysum0; q4.w=0.0f;
        out4[ob          ] = q0;
        out4[ob + 192    ] = q1;
        out4[ob + 2 * 192] = q2;
        out4[ob + 3 * 192] = q3;
        out4[ob + 4 * 192] = q4;
    } else {
        float P[D_STATE];
#pragma unroll
        for (int n = 0; n < D_STATE; n++) P[n] = 1.0f;
#pragma unroll 2
        for (int t = 0; t < CT2; t++) {
            const float4* m4 = (const float4*)&sMeta[t * 20];
            float4 m0 = m4[0], m1 = m4[1], mB0 = m4[2], mB1 = m4[3], mC = m4[4];
            float Bv[6] = {mB0.x, mB0.y, mB0.z, mB0.w, mB1.x, mB1.y};
            float Cv[6] = {mB1.z, mB1.w, mC.x, mC.y, mC.z, mC.w};
            float dr = dtb + m0.x * dtw[0] + m0.y * dtw[1] + m0.z * dtw[2]
                     + m0.w * dtw[3] + m1.x * dtw[4] + m1.y * dtw[5];
            float dl = softplus_fast(dr);
            float xv = bf2f(sxs[t * SXSTR + e]);
            float zw = silu_fast(bf2f(zL[t * SXSTR + e]));
            float dx = dl * xv;
            float y = Dv * xv;
#pragma unroll
            for (int n = 0; n < D_STATE; n++) {
                float dA = __expf(dl * a[n]);
                S[n] = dA * S[n] + dx * Bv[n];
                P[n] *= dA;
                y += S[n] * Cv[n];
                G[n] += zw * P[n] * Cv[n];
            }
            ysum0 += zw * y;
        }
        long ob = (long)(b * NC2 + c) * 5 * 192 + e;
        float4 q0, q1, q2, q3, q4;
        q0.x=P[0]; q0.y=P[1]; q0.z=P[2]; q0.w=P[3];
        q1.x=P[4]; q1.y=P[5]; q1.z=S[0]; q1.w=S[1];
        q2.x=S[2]; q2.y=S[3]; q2.z=S[4]; q2.w=S[5];
        q3.x=G[0]; q3.y=G[1]; q3.z=G[2]; q3.w=G[3];
        q4.x=G[4]; q4.y=G[5]; q4.z=ysum0; q4.w=0.0f;
        out4[ob          ] = q0;
        out4[ob + 192    ] = q1;
        out4[ob + 2 * 192] = q2;
        out4[ob + 3 * 192] = q3;
        out4[ob + 4 * 192] = q4;
    }
}

// ---------------------------------------------------------------------------
// K4S: level-1 fold — compose CPS=8 chunks into one segment.
// ---------------------------------------------------------------------------
__global__ __launch_bounds__(192) void k4_seg(
    const float4* __restrict__ out4, float4* __restrict__ seg4)
{
    const int e = threadIdx.x;
    const int s = blockIdx.x & (NSEG - 1);
    const int b = blockIdx.x >> 4;

    float H[D_STATE], Gq[D_STATE], Pp[D_STATE];
#pragma unroll
    for (int n = 0; n < D_STATE; n++) { H[n] = 0.0f; Gq[n] = 0.0f; Pp[n] = 1.0f; }
    float yb = 0.0f;
#pragma unroll 2
    for (int cc = 0; cc < CPS; cc++) {
        int c = s * CPS + cc;
        long ob = (long)(b * NC2 + c) * 5 * 192 + e;
        float4 q0 = out4[ob];
        float4 q1 = out4[ob + 192];
        float4 q2 = out4[ob + 2 * 192];
        float4 q3 = out4[ob + 3 * 192];
        float4 q4 = out4[ob + 4 * 192];
        float Pv[6] = {q0.x, q0.y, q0.z, q0.w, q1.x, q1.y};
        float Sv[6] = {q1.z, q1.w, q2.x, q2.y, q2.z, q2.w};
        float Gv[6] = {q3.x, q3.y, q3.z, q3.w, q4.x, q4.y};
        float g = 0.0f;
#pragma unroll
        for (int n = 0; n < D_STATE; n++) g += Gv[n] * H[n];
        yb += q4.z + g;
#pragma unroll
        for (int n = 0; n < D_STATE; n++) {
            Gq[n] += Gv[n] * Pp[n];
            H[n] = Pv[n] * H[n] + Sv[n];
            Pp[n] *= Pv[n];
        }
    }
    long sb = (long)(b * NSEG + s) * 5 * 192 + e;
    float4 q0, q1, q2, q3, q4;
    q0.x=Pp[0]; q0.y=Pp[1]; q0.z=Pp[2]; q0.w=Pp[3];
    q1.x=Pp[4]; q1.y=Pp[5]; q1.z=H[0]; q1.w=H[1];
    q2.x=H[2]; q2.y=H[3]; q2.z=H[4]; q2.w=H[5];
    q3.x=Gq[0]; q3.y=Gq[1]; q3.z=Gq[2]; q3.w=Gq[3];
    q4.x=Gq[4]; q4.y=Gq[5]; q4.z=yb; q4.w=0.0f;
    seg4[sb          ] = q0;
    seg4[sb + 192    ] = q1;
    seg4[sb + 2 * 192] = q2;
    seg4[sb + 3 * 192] = q3;
    seg4[sb + 4 * 192] = q4;
}

// ---------------------------------------------------------------------------
// K4H: per-batch block: fold NSEG=16 segments -> ybar; fold 128 xbar
// partials; then output head.
// ---------------------------------------------------------------------------
__global__ __launch_bounds__(192) void k4_head(
    const float4* __restrict__ seg4, const float* __restrict__ xpart,
    const float* __restrict__ Wout,
    const float* __restrict__ fc_w, const float* __restrict__ fc_b,
    const float* __restrict__ mu_w, const float* __restrict__ mu_b,
    const float* __restrict__ sg_w, const float* __restrict__ sg_b,
    float* __restrict__ out)
{
    __shared__ float ybar[D_INNER];
    __shared__ float sxb[D_MODEL];
    __shared__ float evec[D_MODEL];
    __shared__ float feat_s[64];
    const int e = threadIdx.x;
    const int b = blockIdx.x;

    float H[D_STATE];
#pragma unroll
    for (int n = 0; n < D_STATE; n++) H[n] = 0.0f;
    float yb = 0.0f;
#pragma unroll 4
    for (int s = 0; s < NSEG; s++) {
        long ob = (long)(b * NSEG + s) * 5 * 192 + e;
        float4 q0 = seg4[ob];
        float4 q1 = seg4[ob + 192];
        float4 q2 = seg4[ob + 2 * 192];
        float4 q3 = seg4[ob + 3 * 192];
        float4 q4 = seg4[ob + 4 * 192];
        float Pv[6] = {q0.x, q0.y, q0.z, q0.w, q1.x, q1.y};
        float Sv[6] = {q1.z, q1.w, q2.x, q2.y, q2.z, q2.w};
        float Gv[6] = {q3.x, q3.y, q3.z, q3.w, q4.x, q4.y};
        float g = 0.0f;
#pragma unroll
        for (int n = 0; n < D_STATE; n++) g += Gv[n] * H[n];
        yb += q4.z + g;
#pragma unroll
        for (int n = 0; n < D_STATE; n++) H[n] = Pv[n] * H[n] + Sv[n];
    }
    ybar[e] = yb;

    // fold the 128 per-chunk xbar partials for this batch
    if (e < D_MODEL) {
        const float* xp = &xpart[(long)b * NC2 * 96 + e];
        float s = 0.0f;
        for (int t = 0; t < NC2; t++) s += xp[t * 96];
        sxb[e] = s;
    }
    __syncthreads();

    if (e < D_MODEL) {
        float s = sxb[e];
        const float* wrow = &Wout[e * D_INNER];
        for (int e2 = 0; e2 < D_INNER; e2++) s += ybar[e2] * wrow[e2];
        evec[e] = s / (float)SEQLEN;
    }
    __syncthreads();

    if (e < 64) {
        float s = fc_b[e];
        const float* wrow = &fc_w[e * D_MODEL];
        for (int d = 0; d < D_MODEL; d++) s += evec[d] * wrow[d];
        float f = eluf(tanhf(s));
        feat_s[e] = f;
        out[b * 64 + e] = f; // feat
    }
    __syncthreads();

    if (e < 64) {
        float smu = mu_b[e], ssg = sg_b[e];
        const float* mrow = &mu_w[e * 64];
        const float* srow = &sg_w[e * 64];
        for (int i = 0; i < 64; i++) {
            smu += feat_s[i] * mrow[i];
            ssg += feat_s[i] * srow[i];
        }
        out[1024 + b * 64 + e] = smu;                        // mu
        out[2048 + b * 64 + e] = eluf(ssg) + 1.0f + 1e-14f;  // sigma
    }
}

extern "C" void kernel_launch(void* const* d_in, const int* in_sizes, int n_in,
                              void* d_out, int out_size, void* d_ws, size_t ws_size,
                              hipStream_t stream) {
    const float* x         = (const float*)d_in[0];
    const float* in_proj_w = (const float*)d_in[1];
    const float* conv_w    = (const float*)d_in[2];
    const float* conv_b    = (const float*)d_in[3];
    const float* x_proj_w  = (const float*)d_in[4];
    const float* dt_proj_w = (const float*)d_in[5];
    const float* dt_proj_b = (const float*)d_in[6];
    const float* A_log     = (const float*)d_in[7];
    const float* D_param   = (const float*)d_in[8];
    const float* out_proj_w= (const float*)d_in[9];
    const float* norm_w    = (const float*)d_in[10];
    const float* out_fc_w  = (const float*)d_in[11];
    const float* out_fc_b  = (const float*)d_in[12];
    const float* mu_w      = (const float*)d_in[13];
    const float* mu_b      = (const float*)d_in[14];
    const float* sigma_w   = (const float*)d_in[15];
    const float* sigma_b   = (const float*)d_in[16];
    float* ws = (float*)d_ws;
    float* out = (float*)d_out;

    ka_fused<<<BATCH * NC2, 192, 0, stream>>>(
        x, in_proj_w, norm_w, conv_w, conv_b, x_proj_w,
        dt_proj_w, dt_proj_b, A_log, D_param,
        (float4*)(ws + OFF_OUT4), ws + OFF_XPART);

    k4_seg<<<BATCH * NSEG, 192, 0, stream>>>(
        (const float4*)(ws + OFF_OUT4), (float4*)(ws + OFF_SEG));

    k4_head<<<BATCH, 192, 0, stream>>>(
        (const float4*)(ws + OFF_SEG), ws + OFF_XPART, out_proj_w,
        out_fc_w, out_fc_b, mu_w, mu_b, sigma_w, sigma_b, out);
}

// Round 15
// 204.525 us; speedup vs baseline: 1.1616x; 1.1616x over previous
//
#include <hip/hip_runtime.h>
#include <math.h>

#define BATCH 16
#define SEQLEN 4096
#define D_MODEL 96
#define D_STATE 6
#define D_CONV 9
#define D_INNER 192
#define DT_RANK 6
#define NPOS (BATCH * SEQLEN)

#define NC2 128            // chunks per sequence
#define CT2 (SEQLEN / NC2) // 32 steps per chunk
#define NSEG 16            // level-2 segments
#define CPS (NC2 / NSEG)   // chunks per segment = 8

// workspace layout (in floats). xs/z stored as bf16 (ushort).
#define OFF_XS    0L
#define OFF_Z     (OFF_XS   + (long)NPOS * 96)
#define OFF_OUT4  (OFF_Z    + (long)NPOS * 96)       // B*NC2*5*192 float4s
#define OFF_SEG   (OFF_OUT4 + (long)BATCH * NC2 * 5 * 192 * 4)
#define OFF_XPART (OFF_SEG  + (long)BATCH * NSEG * 5 * 192 * 4)  // 1024*96 xbar partials

typedef short v8s __attribute__((ext_vector_type(8)));   // 8 x bf16 (MFMA A/B frag)
typedef float v4f __attribute__((ext_vector_type(4)));   // MFMA C/D frag
typedef float v2f __attribute__((ext_vector_type(2)));   // packed fp32 (v_pk_*_f32)

// fast transcendentals — abs threshold 2e-2, ample headroom
__device__ __forceinline__ float silu_fast(float v) {
    return __fdividef(v, 1.0f + __expf(-v));
}
__device__ __forceinline__ float softplus_fast(float v) {
    return (v > 20.0f) ? v : __logf(1.0f + __expf(v));
}
__device__ __forceinline__ float eluf(float v) {
    return (v > 0.0f) ? v : expm1f(v);
}
__device__ __forceinline__ unsigned int pack_bf16(float a, float b) {
    unsigned int ua = __float_as_uint(a), ub = __float_as_uint(b);
    ua += 0x7FFFu + ((ua >> 16) & 1u);
    ub += 0x7FFFu + ((ub >> 16) & 1u);
    return (ua >> 16) | (ub & 0xFFFF0000u);
}
__device__ __forceinline__ unsigned short bf16h(float v) {
    unsigned int u = __float_as_uint(v);
    u += 0x7FFFu + ((u >> 16) & 1u);
    return (unsigned short)(u >> 16);
}
__device__ __forceinline__ float bf2f(unsigned short h) {
    return __uint_as_float(((unsigned int)h) << 16);
}

// ---------------------------------------------------------------------------
// K1 (MFMA): RMSNorm (fp32) + in_proj via bf16 mfma_f32_16x16x32.
// (round-13 config — known-good ~202-207 total; fusion attempt in round 14
// regressed to 238 via occupancy collapse, reverted)
// ---------------------------------------------------------------------------
#define TP1 64
__global__ __launch_bounds__(256, 2) void k1_rmsnorm_inproj(
    const float* __restrict__ x, const float* __restrict__ W,
    const float* __restrict__ norm_w,
    unsigned short* __restrict__ xs, unsigned short* __restrict__ z,
    float* __restrict__ xpart)
{
    __shared__ unsigned int s_ovl[7680];   // 30.7 KB: hRow (fp32) / WB (bf16 pairs)
    __shared__ unsigned int s_hA[64 * 52]; // 13.3 KB bf16 pairs [pos][dpair]
    __shared__ float s_part[TP1][4];       // 1 KB rms partials
    __shared__ float s_scale[TP1];
    float* hRow = (float*)s_ovl;           // [p][d], stride 101
    unsigned int* WB = s_ovl;              // [j][kpair], stride 20 dw

    const int tid = threadIdx.x;
    const long p0 = (long)blockIdx.x * TP1;

    // stage x as float4 (16B/lane coalesced)
    {
        const float4* x4 = (const float4*)&x[p0 * 96];
        for (int i = tid; i < TP1 * 24; i += 256) {
            int p = i / 24, dq = i - p * 24;
            float4 v = x4[i];
            float* hr = &hRow[p * 101 + dq * 4];
            hr[0] = v.x; hr[1] = v.y; hr[2] = v.z; hr[3] = v.w;
        }
    }
    __syncthreads();

    // rms partials: thread (p, g) sums d = g, g+4, ... (24 terms)
    {
        int p = tid >> 2, g = tid & 3;
        float ss = 0.0f;
        for (int d = g; d < 96; d += 4) { float v = hRow[p * 101 + d]; ss += v * v; }
        s_part[p][g] = ss;
    }
    __syncthreads();

    if (tid < TP1) {
        float ss = s_part[tid][0] + s_part[tid][1] + s_part[tid][2] + s_part[tid][3];
        s_scale[tid] = 1.0f / sqrtf(ss / 96.0f + 1e-5f);
    } else if (tid < TP1 + 96) {
        // xbar partial for this 64-pos tile (plain store — no atomics)
        int d = tid - TP1;
        float s = 0.0f;
        for (int p = 0; p < TP1; p++) s += hRow[p * 101 + d];
        xpart[(long)blockIdx.x * 96 + d] = s;
    }
    __syncthreads();

    {
        const float2* nw2 = (const float2*)norm_w;
        for (int i = tid; i < TP1 * 48; i += 256) {
            int p = i / 48, dp = i - p * 48;
            float sc = s_scale[p];
            float2 nv = nw2[dp];
            float v0 = hRow[p * 101 + 2 * dp]     * sc * nv.x;
            float v1 = hRow[p * 101 + 2 * dp + 1] * sc * nv.y;
            s_hA[p * 52 + dp] = pack_bf16(v0, v1);
        }
    }

    const int wave = tid >> 6, lane = tid & 63;
    const int quad = lane >> 4, ln = lane & 15;
    const int n0 = wave * 96;

    // acc[mt][nt] = D[j-tile nt][pos-tile mt] (swapped operands)
    v4f acc[4][6];
#pragma unroll
    for (int mt = 0; mt < 4; mt++)
#pragma unroll
        for (int nt = 0; nt < 6; nt++) acc[mt][nt] = (v4f){0.f, 0.f, 0.f, 0.f};

    for (int kc = 0; kc < 3; kc++) {
        __syncthreads();
        for (int i = tid; i < 384 * 16; i += 256) {
            int j = i >> 4, kp = i & 15;
            const float2 wv = *(const float2*)&W[j * 96 + kc * 32 + 2 * kp];
            WB[j * 20 + kp] = pack_bf16(wv.x, wv.y);
        }
        __syncthreads();

        v8s bfh[4];   // h fragments (B operand)
#pragma unroll
        for (int mt = 0; mt < 4; mt++)
            bfh[mt] = *(const v8s*)&s_hA[(mt * 16 + ln) * 52 + kc * 16 + quad * 4];
#pragma unroll
        for (int nt = 0; nt < 6; nt++) {
            v8s aw = *(const v8s*)&WB[(n0 + nt * 16 + ln) * 20 + quad * 4];
#pragma unroll
            for (int mt = 0; mt < 4; mt++)
                acc[mt][nt] = __builtin_amdgcn_mfma_f32_16x16x32_bf16(
                    aw, bfh[mt], acc[mt][nt], 0, 0, 0);
        }
    }

    // epilogue: D[j][pos] — lane owns j = quad*4+r (consecutive), pos = ln.
    unsigned short* dst = (wave < 2) ? xs : z;
    const int jb = (wave & 1) * 96;
#pragma unroll
    for (int mt = 0; mt < 4; mt++) {
        long pos = p0 + mt * 16 + ln;
#pragma unroll
        for (int nt = 0; nt < 6; nt++) {
            uint2 v;
            v.x = pack_bf16(acc[mt][nt][0], acc[mt][nt][1]);
            v.y = pack_bf16(acc[mt][nt][2], acc[mt][nt][3]);
            *(uint2*)&dst[pos * D_INNER + jb + nt * 16 + quad * 4] = v;
        }
    }
}

// ---------------------------------------------------------------------------
// K2F: conv+silu -> xc (bf16 LDS); dbc GEMM via MFMA; chunk scan with the
// n-loop packed into 3 x float2 (v_pk_fma_f32/v_pk_mul_f32 on gfx950 —
// full-rate packed fp32). launch_bounds(192,4): VGPR 60, no spill.
// ---------------------------------------------------------------------------
#define SXSTR 200   // ushort stride; 100 dw, %32=4 -> bank spread; 16B-aligned
__global__ __launch_bounds__(192, 4) void k2f_conv_scan(
    const unsigned short* __restrict__ xs, const unsigned short* __restrict__ z,
    const float* __restrict__ conv_w, const float* __restrict__ conv_b,
    const float* __restrict__ x_proj_w,
    const float* __restrict__ dt_w, const float* __restrict__ dt_b,
    const float* __restrict__ A_log, const float* __restrict__ D_param,
    float4* __restrict__ out4)
{
    __shared__ unsigned short sxc[CT2 * SXSTR];   // 12.8 KB xc tile [t][e] bf16
    __shared__ unsigned short sxpB[18 * SXSTR];   // 7.2 KB x_proj_w bf16
    __shared__ float sMeta[CT2][20];              // 2.56 KB: [0:6) dr, [8:14) Bm, [14:20) Cm
    const int e = threadIdx.x;
    const int c = blockIdx.x & (NC2 - 1);
    const int b = blockIdx.x >> 7;
    const int l0 = c * CT2;
    const long brow = (long)b * SEQLEN;

    // stage x_proj_w (18x192) as bf16
    {
        unsigned int* xpB = (unsigned int*)sxpB;
        for (int i = e; i < 18 * 96; i += 192) {
            int f = i / 96, kp = i - f * 96;
            const float2 wv = *(const float2*)&x_proj_w[f * 192 + 2 * kp];
            xpB[f * 100 + kp] = pack_bf16(wv.x, wv.y);
        }
    }

    // conv + silu -> sxc (bf16), fully unrolled rolling window
    float cw[D_CONV];
#pragma unroll
    for (int k = 0; k < D_CONV; k++) cw[k] = conv_w[e * D_CONV + k];
    const float cb = conv_b[e];
    float win[D_CONV];
#pragma unroll
    for (int k = 0; k < 8; k++) {
        int ll = l0 - 8 + k;
        win[k] = (ll >= 0) ? bf2f(xs[(brow + ll) * D_INNER + e]) : 0.0f;
    }
#pragma unroll
    for (int r = 0; r < CT2; r++) {
        win[8] = bf2f(xs[(brow + l0 + r) * D_INNER + e]);
        float s = cb;
#pragma unroll
        for (int k = 0; k < D_CONV; k++) s += win[k] * cw[k];
        sxc[r * SXSTR + e] = bf16h(silu_fast(s));
#pragma unroll
        for (int k = 0; k < 8; k++) win[k] = win[k + 1];
    }

    // prefetch z for the whole chunk (independent loads in flight)
    const unsigned short* zp = &z[(brow + l0) * D_INNER + e];
    float zv[CT2];
#pragma unroll
    for (int t = 0; t < CT2; t++) zv[t] = bf2f(zp[(long)t * D_INNER]);
    __syncthreads();

    // dbc GEMM via MFMA: D[pos][f] = sum_e xc[pos][e] * xp[f][e].
    {
        const int wave = e >> 6, lane = e & 63;
        const int quad = lane >> 4, ln = lane & 15;
        if (wave < 2) {
            const int mt = wave;
            const int r1 = (ln < 2) ? 16 + ln : 0;   // clamp: f>=18 cols discarded
            v4f dacc[2];
            dacc[0] = (v4f){0.f, 0.f, 0.f, 0.f};
            dacc[1] = (v4f){0.f, 0.f, 0.f, 0.f};
#pragma unroll
            for (int kc = 0; kc < 6; kc++) {
                v8s af  = *(const v8s*)&sxc[(mt * 16 + ln) * SXSTR + kc * 32 + quad * 8];
                v8s bf0 = *(const v8s*)&sxpB[ln * SXSTR + kc * 32 + quad * 8];
                v8s bf1 = *(const v8s*)&sxpB[r1 * SXSTR + kc * 32 + quad * 8];
                dacc[0] = __builtin_amdgcn_mfma_f32_16x16x32_bf16(af, bf0, dacc[0], 0, 0, 0);
                dacc[1] = __builtin_amdgcn_mfma_f32_16x16x32_bf16(af, bf1, dacc[1], 0, 0, 0);
            }
#pragma unroll
            for (int nt = 0; nt < 2; nt++) {
                int f = nt * 16 + ln;
                if (f < 18) {
                    int col = (f < 6) ? f : f + 2;
#pragma unroll
                    for (int r = 0; r < 4; r++)
                        sMeta[mt * 16 + quad * 4 + r][col] = dacc[nt][r];
                }
            }
        }
    }
    __syncthreads();

    float a[D_STATE];
#pragma unroll
    for (int n = 0; n < D_STATE; n++) a[n] = -__expf(A_log[e * D_STATE + n]);
    float dtw[DT_RANK];
#pragma unroll
    for (int q = 0; q < DT_RANK; q++) dtw[q] = dt_w[e * DT_RANK + q];
    const float dtb = dt_b[e];
    const float Dv = D_param[e];
    const float a0 = a[0];

    // structure check: a[n] == (n+1)*a0 (true for A_log = log(tile(1..6)))
    bool pok = true;
#pragma unroll
    for (int n = 1; n < D_STATE; n++)
        pok = pok && (fabsf(a[n] - (float)(n + 1) * a0)
                      <= 1e-4f * (float)(n + 1) * fabsf(a0));
    unsigned long long pmask = __ballot(pok);

    if (pmask == 0xFFFFFFFFFFFFFFFFull) {
        // power-chain path, packed: dA pairs {E,E2},{E3,E4},{E5,E6};
        // P pairs likewise from Pa. S/G/y ops in float2 -> v_pk_fma_f32.
        v2f S01 = {0.f, 0.f}, S23 = {0.f, 0.f}, S45 = {0.f, 0.f};
        v2f G01 = {0.f, 0.f}, G23 = {0.f, 0.f}, G45 = {0.f, 0.f};
        float ysum0 = 0.0f;
        float Pa = 1.0f;
#pragma unroll 2
        for (int t = 0; t < CT2; t++) {
            const float4* m4 = (const float4*)&sMeta[t][0];
            float4 m0 = m4[0], m1 = m4[1], mB0 = m4[2], mB1 = m4[3], mC = m4[4];
            v2f B01 = {mB0.x, mB0.y}, B23 = {mB0.z, mB0.w}, B45 = {mB1.x, mB1.y};
            v2f C01 = {mB1.z, mB1.w}, C23 = {mC.x, mC.y},  C45 = {mC.z, mC.w};
            float dr = dtb + m0.x * dtw[0] + m0.y * dtw[1] + m0.z * dtw[2]
                     + m0.w * dtw[3] + m1.x * dtw[4] + m1.y * dtw[5];
            float dl = softplus_fast(dr);
            float xv = bf2f(sxc[t * SXSTR + e]);
            float zw = silu_fast(zv[t]);
            float dx = dl * xv;
            float E = __expf(dl * a0);
            float E2 = E * E;
            Pa *= E;
            float Pa2 = Pa * Pa;
            v2f dA01 = {E, E2};
            v2f dA23 = dA01 * E2;
            v2f dA45 = dA23 * E2;
            v2f P01 = {Pa, Pa2};
            v2f P23 = P01 * Pa2;
            v2f P45 = P23 * Pa2;
            S01 = dA01 * S01 + dx * B01;
            S23 = dA23 * S23 + dx * B23;
            S45 = dA45 * S45 + dx * B45;
            v2f yv = S01 * C01 + S23 * C23 + S45 * C45;
            G01 += (zw * P01) * C01;
            G23 += (zw * P23) * C23;
            G45 += (zw * P45) * C45;
            ysum0 += zw * (Dv * xv + yv.x + yv.y);
        }
        long ob = (long)(b * NC2 + c) * 5 * 192 + e;
        float P1 = Pa, P2 = P1 * Pa, P3 = P2 * Pa, P4 = P3 * Pa, P5 = P4 * Pa, P6 = P5 * Pa;
        float4 q0, q1, q2, q3, q4;
        q0.x=P1; q0.y=P2; q0.z=P3; q0.w=P4;
        q1.x=P5; q1.y=P6; q1.z=S01.x; q1.w=S01.y;
        q2.x=S23.x; q2.y=S23.y; q2.z=S45.x; q2.w=S45.y;
        q3.x=G01.x; q3.y=G01.y; q3.z=G23.x; q3.w=G23.y;
        q4.x=G45.x; q4.y=G45.y; q4.z=ysum0; q4.w=0.0f;
        out4[ob          ] = q0;
        out4[ob + 192    ] = q1;
        out4[ob + 2 * 192] = q2;
        out4[ob + 3 * 192] = q3;
        out4[ob + 4 * 192] = q4;
    } else {
        // generic path (scalar, rarely taken)
        float S[D_STATE], G[D_STATE], P[D_STATE];
#pragma unroll
        for (int n = 0; n < D_STATE; n++) { S[n] = 0.0f; G[n] = 0.0f; P[n] = 1.0f; }
        float ysum0 = 0.0f;
#pragma unroll 2
        for (int t = 0; t < CT2; t++) {
            const float4* m4 = (const float4*)&sMeta[t][0];
            float4 m0 = m4[0], m1 = m4[1], mB0 = m4[2], mB1 = m4[3], mC = m4[4];
            float Bv[6] = {mB0.x, mB0.y, mB0.z, mB0.w, mB1.x, mB1.y};
            float Cv[6] = {mB1.z, mB1.w, mC.x, mC.y, mC.z, mC.w};
            float dr = dtb + m0.x * dtw[0] + m0.y * dtw[1] + m0.z * dtw[2]
                     + m0.w * dtw[3] + m1.x * dtw[4] + m1.y * dtw[5];
            float dl = softplus_fast(dr);
            float xv = bf2f(sxc[t * SXSTR + e]);
            float zw = silu_fast(zv[t]);
            float dx = dl * xv;
            float y = Dv * xv;
#pragma unroll
            for (int n = 0; n < D_STATE; n++) {
                float dA = __expf(dl * a[n]);
                S[n] = dA * S[n] + dx * Bv[n];
                P[n] *= dA;
                y += S[n] * Cv[n];
                G[n] += zw * P[n] * Cv[n];
            }
            ysum0 += zw * y;
        }
        long ob = (long)(b * NC2 + c) * 5 * 192 + e;
        float4 q0, q1, q2, q3, q4;
        q0.x=P[0]; q0.y=P[1]; q0.z=P[2]; q0.w=P[3];
        q1.x=P[4]; q1.y=P[5]; q1.z=S[0]; q1.w=S[1];
        q2.x=S[2]; q2.y=S[3]; q2.z=S[4]; q2.w=S[5];
        q3.x=G[0]; q3.y=G[1]; q3.z=G[2]; q3.w=G[3];
        q4.x=G[4]; q4.y=G[5]; q4.z=ysum0; q4.w=0.0f;
        out4[ob          ] = q0;
        out4[ob + 192    ] = q1;
        out4[ob + 2 * 192] = q2;
        out4[ob + 3 * 192] = q3;
        out4[ob + 4 * 192] = q4;
    }
}

// ---------------------------------------------------------------------------
// K4S: level-1 fold — compose CPS=8 chunks into one segment.
// ---------------------------------------------------------------------------
__global__ __launch_bounds__(192) void k4_seg(
    const float4* __restrict__ out4, float4* __restrict__ seg4)
{
    const int e = threadIdx.x;
    const int s = blockIdx.x & (NSEG - 1);
    const int b = blockIdx.x >> 4;

    float H[D_STATE], Gq[D_STATE], Pp[D_STATE];
#pragma unroll
    for (int n = 0; n < D_STATE; n++) { H[n] = 0.0f; Gq[n] = 0.0f; Pp[n] = 1.0f; }
    float yb = 0.0f;
#pragma unroll 2
    for (int cc = 0; cc < CPS; cc++) {
        int c = s * CPS + cc;
        long ob = (long)(b * NC2 + c) * 5 * 192 + e;
        float4 q0 = out4[ob];
        float4 q1 = out4[ob + 192];
        float4 q2 = out4[ob + 2 * 192];
        float4 q3 = out4[ob + 3 * 192];
        float4 q4 = out4[ob + 4 * 192];
        float Pv[6] = {q0.x, q0.y, q0.z, q0.w, q1.x, q1.y};
        float Sv[6] = {q1.z, q1.w, q2.x, q2.y, q2.z, q2.w};
        float Gv[6] = {q3.x, q3.y, q3.z, q3.w, q4.x, q4.y};
        float g = 0.0f;
#pragma unroll
        for (int n = 0; n < D_STATE; n++) g += Gv[n] * H[n];
        yb += q4.z + g;
#pragma unroll
        for (int n = 0; n < D_STATE; n++) {
            Gq[n] += Gv[n] * Pp[n];
            H[n] = Pv[n] * H[n] + Sv[n];
            Pp[n] *= Pv[n];
        }
    }
    long sb = (long)(b * NSEG + s) * 5 * 192 + e;
    float4 q0, q1, q2, q3, q4;
    q0.x=Pp[0]; q0.y=Pp[1]; q0.z=Pp[2]; q0.w=Pp[3];
    q1.x=Pp[4]; q1.y=Pp[5]; q1.z=H[0]; q1.w=H[1];
    q2.x=H[2]; q2.y=H[3]; q2.z=H[4]; q2.w=H[5];
    q3.x=Gq[0]; q3.y=Gq[1]; q3.z=Gq[2]; q3.w=Gq[3];
    q4.x=Gq[4]; q4.y=Gq[5]; q4.z=yb; q4.w=0.0f;
    seg4[sb          ] = q0;
    seg4[sb + 192    ] = q1;
    seg4[sb + 2 * 192] = q2;
    seg4[sb + 3 * 192] = q3;
    seg4[sb + 4 * 192] = q4;
}

// ---------------------------------------------------------------------------
// K4H: per-batch block: fold NSEG=16 segments -> ybar; fold 64 xbar
// partials; then output head.
// ---------------------------------------------------------------------------
__global__ __launch_bounds__(192) void k4_head(
    const float4* __restrict__ seg4, const float* __restrict__ xpart,
    const float* __restrict__ Wout,
    const float* __restrict__ fc_w, const float* __restrict__ fc_b,
    const float* __restrict__ mu_w, const float* __restrict__ mu_b,
    const float* __restrict__ sg_w, const float* __restrict__ sg_b,
    float* __restrict__ out)
{
    __shared__ float ybar[D_INNER];
    __shared__ float sxb[D_MODEL];
    __shared__ float evec[D_MODEL];
    __shared__ float feat_s[64];
    const int e = threadIdx.x;
    const int b = blockIdx.x;

    float H[D_STATE];
#pragma unroll
    for (int n = 0; n < D_STATE; n++) H[n] = 0.0f;
    float yb = 0.0f;
#pragma unroll 4
    for (int s = 0; s < NSEG; s++) {
        long ob = (long)(b * NSEG + s) * 5 * 192 + e;
        float4 q0 = seg4[ob];
        float4 q1 = seg4[ob + 192];
        float4 q2 = seg4[ob + 2 * 192];
        float4 q3 = seg4[ob + 3 * 192];
        float4 q4 = seg4[ob + 4 * 192];
        float Pv[6] = {q0.x, q0.y, q0.z, q0.w, q1.x, q1.y};
        float Sv[6] = {q1.z, q1.w, q2.x, q2.y, q2.z, q2.w};
        float Gv[6] = {q3.x, q3.y, q3.z, q3.w, q4.x, q4.y};
        float g = 0.0f;
#pragma unroll
        for (int n = 0; n < D_STATE; n++) g += Gv[n] * H[n];
        yb += q4.z + g;
#pragma unroll
        for (int n = 0; n < D_STATE; n++) H[n] = Pv[n] * H[n] + Sv[n];
    }
    ybar[e] = yb;

    // fold the 64 per-tile xbar partials for this batch
    if (e < D_MODEL) {
        const float* xp = &xpart[(long)b * 64 * 96 + e];
        float s = 0.0f;
        for (int t = 0; t < 64; t++) s += xp[t * 96];
        sxb[e] = s;
    }
    __syncthreads();

    if (e < D_MODEL) {
        float s = sxb[e];
        const float* wrow = &Wout[e * D_INNER];
        for (int e2 = 0; e2 < D_INNER; e2++) s += ybar[e2] * wrow[e2];
        evec[e] = s / (float)SEQLEN;
    }
    __syncthreads();

    if (e < 64) {
        float s = fc_b[e];
        const float* wrow = &fc_w[e * D_MODEL];
        for (int d = 0; d < D_MODEL; d++) s += evec[d] * wrow[d];
        float f = eluf(tanhf(s));
        feat_s[e] = f;
        out[b * 64 + e] = f; // feat
    }
    __syncthreads();

    if (e < 64) {
        float smu = mu_b[e], ssg = sg_b[e];
        const float* mrow = &mu_w[e * 64];
        const float* srow = &sg_w[e * 64];
        for (int i = 0; i < 64; i++) {
            smu += feat_s[i] * mrow[i];
            ssg += feat_s[i] * srow[i];
        }
        out[1024 + b * 64 + e] = smu;                        // mu
        out[2048 + b * 64 + e] = eluf(ssg) + 1.0f + 1e-14f;  // sigma
    }
}

extern "C" void kernel_launch(void* const* d_in, const int* in_sizes, int n_in,
                              void* d_out, int out_size, void* d_ws, size_t ws_size,
                              hipStream_t stream) {
    const float* x         = (const float*)d_in[0];
    const float* in_proj_w = (const float*)d_in[1];
    const float* conv_w    = (const float*)d_in[2];
    const float* conv_b    = (const float*)d_in[3];
    const float* x_proj_w  = (const float*)d_in[4];
    const float* dt_proj_w = (const float*)d_in[5];
    const float* dt_proj_b = (const float*)d_in[6];
    const float* A_log     = (const float*)d_in[7];
    const float* D_param   = (const float*)d_in[8];
    const float* out_proj_w= (const float*)d_in[9];
    const float* norm_w    = (const float*)d_in[10];
    const float* out_fc_w  = (const float*)d_in[11];
    const float* out_fc_b  = (const float*)d_in[12];
    const float* mu_w      = (const float*)d_in[13];
    const float* mu_b      = (const float*)d_in[14];
    const float* sigma_w   = (const float*)d_in[15];
    const float* sigma_b   = (const float*)d_in[16];
    float* ws = (float*)d_ws;
    float* out = (float*)d_out;

    k1_rmsnorm_inproj<<<NPOS / TP1, 256, 0, stream>>>(
        x, in_proj_w, norm_w,
        (unsigned short*)(ws + OFF_XS), (unsigned short*)(ws + OFF_Z),
        ws + OFF_XPART);

    k2f_conv_scan<<<BATCH * NC2, 192, 0, stream>>>(
        (const unsigned short*)(ws + OFF_XS), (const unsigned short*)(ws + OFF_Z),
        conv_w, conv_b, x_proj_w,
        dt_proj_w, dt_proj_b, A_log, D_param,
        (float4*)(ws + OFF_OUT4));

    k4_seg<<<BATCH * NSEG, 192, 0, stream>>>(
        (const float4*)(ws + OFF_OUT4), (float4*)(ws + OFF_SEG));

    k4_head<<<BATCH, 192, 0, stream>>>(
        (const float4*)(ws + OFF_SEG), ws + OFF_XPART, out_proj_w,
        out_fc_w, out_fc_b, mu_w, mu_b, sigma_w, sigma_b, out);
}

// Round 16
// 202.120 us; speedup vs baseline: 1.1754x; 1.0119x over previous
//
#include <hip/hip_runtime.h>
#include <math.h>

#define BATCH 16
#define SEQLEN 4096
#define D_MODEL 96
#define D_STATE 6
#define D_CONV 9
#define D_INNER 192
#define DT_RANK 6
#define NPOS (BATCH * SEQLEN)

#define NC2 128            // chunks per sequence
#define CT2 (SEQLEN / NC2) // 32 steps per chunk
#define NSEG 16            // level-2 segments
#define CPS (NC2 / NSEG)   // chunks per segment = 8

// workspace layout (in floats). xs/z stored as bf16 (ushort).
#define OFF_XS    0L
#define OFF_Z     (OFF_XS   + (long)NPOS * 96)
#define OFF_OUT4  (OFF_Z    + (long)NPOS * 96)       // B*NC2*5*192 float4s
#define OFF_SEG   (OFF_OUT4 + (long)BATCH * NC2 * 5 * 192 * 4)
#define OFF_XPART (OFF_SEG  + (long)BATCH * NSEG * 5 * 192 * 4)  // 1024*96 xbar partials

typedef short v8s __attribute__((ext_vector_type(8)));   // 8 x bf16 (MFMA A/B frag)
typedef float v4f __attribute__((ext_vector_type(4)));   // MFMA C/D frag

// fast transcendentals — abs threshold 2e-2, ample headroom
__device__ __forceinline__ float silu_fast(float v) {
    return __fdividef(v, 1.0f + __expf(-v));
}
__device__ __forceinline__ float softplus_fast(float v) {
    return (v > 20.0f) ? v : __logf(1.0f + __expf(v));
}
__device__ __forceinline__ float eluf(float v) {
    return (v > 0.0f) ? v : expm1f(v);
}
__device__ __forceinline__ unsigned int pack_bf16(float a, float b) {
    unsigned int ua = __float_as_uint(a), ub = __float_as_uint(b);
    ua += 0x7FFFu + ((ua >> 16) & 1u);
    ub += 0x7FFFu + ((ub >> 16) & 1u);
    return (ua >> 16) | (ub & 0xFFFF0000u);
}
__device__ __forceinline__ unsigned short bf16h(float v) {
    unsigned int u = __float_as_uint(v);
    u += 0x7FFFu + ((u >> 16) & 1u);
    return (unsigned short)(u >> 16);
}
__device__ __forceinline__ float bf2f(unsigned short h) {
    return __uint_as_float(((unsigned int)h) << 16);
}

// ---------------------------------------------------------------------------
// K1 (MFMA): RMSNorm (fp32) + in_proj via bf16 mfma_f32_16x16x32.
// Round 16: BARRIER-FREE K-loop. Wave w consumes only W rows
// [w*96, w*96+96), so staging is wave-private: each wave packs its own
// 96x16 bf16 region (7.7 KB slice of the hRow-overlaid WB) and MFMAs from
// it with no __syncthreads — intra-wave LDS order is enforced by the
// compiler's lgkmcnt/vmcnt waits. Kills the 6 K-loop barriers that
// serialized all waves on every W-stage (the suspected ~40 us stall).
// One sync remains after normalize (hA ready / hRow dead).
// ---------------------------------------------------------------------------
#define TP1 64
__global__ __launch_bounds__(256, 2) void k1_rmsnorm_inproj(
    const float* __restrict__ x, const float* __restrict__ W,
    const float* __restrict__ norm_w,
    unsigned short* __restrict__ xs, unsigned short* __restrict__ z,
    float* __restrict__ xpart)
{
    __shared__ unsigned int s_ovl[7680];   // 30.7 KB: hRow fp32[64*101] / WB 4 x 1920 dw
    __shared__ unsigned int s_hA[64 * 52]; // 13.3 KB bf16 pairs [pos][dpair]
    __shared__ float s_part[TP1][4];       // 1 KB rms partials
    __shared__ float s_scale[TP1];
    float* hRow = (float*)s_ovl;           // [p][d], stride 101
    unsigned int* WB = s_ovl;              // 4 wave-private regions, [j'][kpair] stride 20

    const int tid = threadIdx.x;
    const long p0 = (long)blockIdx.x * TP1;

    // stage x as float4 (16B/lane coalesced)
    {
        const float4* x4 = (const float4*)&x[p0 * 96];
        for (int i = tid; i < TP1 * 24; i += 256) {
            int p = i / 24, dq = i - p * 24;
            float4 v = x4[i];
            float* hr = &hRow[p * 101 + dq * 4];
            hr[0] = v.x; hr[1] = v.y; hr[2] = v.z; hr[3] = v.w;
        }
    }
    __syncthreads();

    // rms partials: thread (p, g) sums d = g, g+4, ... (24 terms)
    {
        int p = tid >> 2, g = tid & 3;
        float ss = 0.0f;
        for (int d = g; d < 96; d += 4) { float v = hRow[p * 101 + d]; ss += v * v; }
        s_part[p][g] = ss;
    }
    __syncthreads();

    if (tid < TP1) {
        float ss = s_part[tid][0] + s_part[tid][1] + s_part[tid][2] + s_part[tid][3];
        s_scale[tid] = 1.0f / sqrtf(ss / 96.0f + 1e-5f);
    } else if (tid < TP1 + 96) {
        // xbar partial for this 64-pos tile (plain store — no atomics)
        int d = tid - TP1;
        float s = 0.0f;
        for (int p = 0; p < TP1; p++) s += hRow[p * 101 + d];
        xpart[(long)blockIdx.x * 96 + d] = s;
    }
    __syncthreads();

    {
        const float2* nw2 = (const float2*)norm_w;
        for (int i = tid; i < TP1 * 48; i += 256) {
            int p = i / 48, dp = i - p * 48;
            float sc = s_scale[p];
            float2 nv = nw2[dp];
            float v0 = hRow[p * 101 + 2 * dp]     * sc * nv.x;
            float v1 = hRow[p * 101 + 2 * dp + 1] * sc * nv.y;
            s_hA[p * 52 + dp] = pack_bf16(v0, v1);
        }
    }
    __syncthreads();   // hA complete; hRow dead -> WB regions free

    const int wave = tid >> 6, lane = tid & 63;
    const int quad = lane >> 4, ln = lane & 15;
    const int n0 = wave * 96;
    unsigned int* WBw = WB + wave * 1920;   // wave-private 96x(16+4pad) region

    // acc[mt][nt] = D[j-tile nt][pos-tile mt] (operand-swapped mfma(W,h))
    v4f acc[4][6];
#pragma unroll
    for (int mt = 0; mt < 4; mt++)
#pragma unroll
        for (int nt = 0; nt < 6; nt++) acc[mt][nt] = (v4f){0.f, 0.f, 0.f, 0.f};

    for (int kc = 0; kc < 3; kc++) {
        // wave-private W staging: 24 bf16-pairs per lane, no barrier
#pragma unroll 8
        for (int ii = 0; ii < 24; ii++) {
            int i = lane + ii * 64;
            int jp = i >> 4, kp = i & 15;
            const float2 wv = *(const float2*)&W[(n0 + jp) * 96 + kc * 32 + 2 * kp];
            WBw[jp * 20 + kp] = pack_bf16(wv.x, wv.y);
        }
        // compiler inserts lgkmcnt wait before these dependent ds_reads
        v8s bfh[4];
#pragma unroll
        for (int mt = 0; mt < 4; mt++)
            bfh[mt] = *(const v8s*)&s_hA[(mt * 16 + ln) * 52 + kc * 16 + quad * 4];
#pragma unroll
        for (int nt = 0; nt < 6; nt++) {
            v8s aw = *(const v8s*)&WBw[(nt * 16 + ln) * 20 + quad * 4];
#pragma unroll
            for (int mt = 0; mt < 4; mt++)
                acc[mt][nt] = __builtin_amdgcn_mfma_f32_16x16x32_bf16(
                    aw, bfh[mt], acc[mt][nt], 0, 0, 0);
        }
    }

    // epilogue: D[j][pos] — lane owns j = quad*4+r (consecutive), pos = ln.
    unsigned short* dst = (wave < 2) ? xs : z;
    const int jb = (wave & 1) * 96;
#pragma unroll
    for (int mt = 0; mt < 4; mt++) {
        long pos = p0 + mt * 16 + ln;
#pragma unroll
        for (int nt = 0; nt < 6; nt++) {
            uint2 v;
            v.x = pack_bf16(acc[mt][nt][0], acc[mt][nt][1]);
            v.y = pack_bf16(acc[mt][nt][2], acc[mt][nt][3]);
            *(uint2*)&dst[pos * D_INNER + jb + nt * 16 + quad * 4] = v;
        }
    }
}

// ---------------------------------------------------------------------------
// K2F: conv+silu -> xc (bf16 LDS); dbc GEMM via MFMA; chunk scan (G-trick,
// power-chain exp, scalar-Pa). Round-13 form (scalar scan — round-15's
// float2 packing regressed k2f 60->68, reverted). launch_bounds(192,4).
// ---------------------------------------------------------------------------
#define SXSTR 200   // ushort stride; 100 dw, %32=4 -> bank spread; 16B-aligned
__global__ __launch_bounds__(192, 4) void k2f_conv_scan(
    const unsigned short* __restrict__ xs, const unsigned short* __restrict__ z,
    const float* __restrict__ conv_w, const float* __restrict__ conv_b,
    const float* __restrict__ x_proj_w,
    const float* __restrict__ dt_w, const float* __restrict__ dt_b,
    const float* __restrict__ A_log, const float* __restrict__ D_param,
    float4* __restrict__ out4)
{
    __shared__ unsigned short sxc[CT2 * SXSTR];   // 12.8 KB xc tile [t][e] bf16
    __shared__ unsigned short sxpB[18 * SXSTR];   // 7.2 KB x_proj_w bf16
    __shared__ float sMeta[CT2][20];              // 2.56 KB: [0:6) dr, [8:14) Bm, [14:20) Cm
    const int e = threadIdx.x;
    const int c = blockIdx.x & (NC2 - 1);
    const int b = blockIdx.x >> 7;
    const int l0 = c * CT2;
    const long brow = (long)b * SEQLEN;

    // stage x_proj_w (18x192) as bf16
    {
        unsigned int* xpB = (unsigned int*)sxpB;
        for (int i = e; i < 18 * 96; i += 192) {
            int f = i / 96, kp = i - f * 96;
            const float2 wv = *(const float2*)&x_proj_w[f * 192 + 2 * kp];
            xpB[f * 100 + kp] = pack_bf16(wv.x, wv.y);
        }
    }

    // conv + silu -> sxc (bf16), fully unrolled rolling window
    float cw[D_CONV];
#pragma unroll
    for (int k = 0; k < D_CONV; k++) cw[k] = conv_w[e * D_CONV + k];
    const float cb = conv_b[e];
    float win[D_CONV];
#pragma unroll
    for (int k = 0; k < 8; k++) {
        int ll = l0 - 8 + k;
        win[k] = (ll >= 0) ? bf2f(xs[(brow + ll) * D_INNER + e]) : 0.0f;
    }
#pragma unroll
    for (int r = 0; r < CT2; r++) {
        win[8] = bf2f(xs[(brow + l0 + r) * D_INNER + e]);
        float s = cb;
#pragma unroll
        for (int k = 0; k < D_CONV; k++) s += win[k] * cw[k];
        sxc[r * SXSTR + e] = bf16h(silu_fast(s));
#pragma unroll
        for (int k = 0; k < 8; k++) win[k] = win[k + 1];
    }

    // prefetch z for the whole chunk (independent loads in flight)
    const unsigned short* zp = &z[(brow + l0) * D_INNER + e];
    float zv[CT2];
#pragma unroll
    for (int t = 0; t < CT2; t++) zv[t] = bf2f(zp[(long)t * D_INNER]);
    __syncthreads();

    // dbc GEMM via MFMA: D[pos][f] = sum_e xc[pos][e] * xp[f][e].
    {
        const int wave = e >> 6, lane = e & 63;
        const int quad = lane >> 4, ln = lane & 15;
        if (wave < 2) {
            const int mt = wave;
            const int r1 = (ln < 2) ? 16 + ln : 0;   // clamp: f>=18 cols discarded
            v4f dacc[2];
            dacc[0] = (v4f){0.f, 0.f, 0.f, 0.f};
            dacc[1] = (v4f){0.f, 0.f, 0.f, 0.f};
#pragma unroll
            for (int kc = 0; kc < 6; kc++) {
                v8s af  = *(const v8s*)&sxc[(mt * 16 + ln) * SXSTR + kc * 32 + quad * 8];
                v8s bf0 = *(const v8s*)&sxpB[ln * SXSTR + kc * 32 + quad * 8];
                v8s bf1 = *(const v8s*)&sxpB[r1 * SXSTR + kc * 32 + quad * 8];
                dacc[0] = __builtin_amdgcn_mfma_f32_16x16x32_bf16(af, bf0, dacc[0], 0, 0, 0);
                dacc[1] = __builtin_amdgcn_mfma_f32_16x16x32_bf16(af, bf1, dacc[1], 0, 0, 0);
            }
#pragma unroll
            for (int nt = 0; nt < 2; nt++) {
                int f = nt * 16 + ln;
                if (f < 18) {
                    int col = (f < 6) ? f : f + 2;
#pragma unroll
                    for (int r = 0; r < 4; r++)
                        sMeta[mt * 16 + quad * 4 + r][col] = dacc[nt][r];
                }
            }
        }
    }
    __syncthreads();

    float a[D_STATE];
#pragma unroll
    for (int n = 0; n < D_STATE; n++) a[n] = -__expf(A_log[e * D_STATE + n]);
    float dtw[DT_RANK];
#pragma unroll
    for (int q = 0; q < DT_RANK; q++) dtw[q] = dt_w[e * DT_RANK + q];
    const float dtb = dt_b[e];
    const float Dv = D_param[e];
    const float a0 = a[0];

    // structure check: a[n] == (n+1)*a0 (true for A_log = log(tile(1..6)))
    bool pok = true;
#pragma unroll
    for (int n = 1; n < D_STATE; n++)
        pok = pok && (fabsf(a[n] - (float)(n + 1) * a0)
                      <= 1e-4f * (float)(n + 1) * fabsf(a0));
    unsigned long long pmask = __ballot(pok);

    float S[D_STATE], G[D_STATE];
#pragma unroll
    for (int n = 0; n < D_STATE; n++) { S[n] = 0.0f; G[n] = 0.0f; }
    float ysum0 = 0.0f;

    if (pmask == 0xFFFFFFFFFFFFFFFFull) {
        // power-chain path: dA[n] = E^(n+1); P[n] = Pa^(n+1), Pa scalar.
        float Pa = 1.0f;
#pragma unroll 2
        for (int t = 0; t < CT2; t++) {
            const float4* m4 = (const float4*)&sMeta[t][0];
            float4 m0 = m4[0], m1 = m4[1], mB0 = m4[2], mB1 = m4[3], mC = m4[4];
            float Bv[6] = {mB0.x, mB0.y, mB0.z, mB0.w, mB1.x, mB1.y};
            float Cv[6] = {mB1.z, mB1.w, mC.x, mC.y, mC.z, mC.w};
            float dr = dtb + m0.x * dtw[0] + m0.y * dtw[1] + m0.z * dtw[2]
                     + m0.w * dtw[3] + m1.x * dtw[4] + m1.y * dtw[5];
            float dl = softplus_fast(dr);
            float xv = bf2f(sxc[t * SXSTR + e]);
            float zw = silu_fast(zv[t]);
            float dx = dl * xv;
            float y = Dv * xv;
            float E = __expf(dl * a0);
            Pa *= E;
            float dA = E, Pn = Pa;
#pragma unroll
            for (int n = 0; n < D_STATE; n++) {
                S[n] = dA * S[n] + dx * Bv[n];
                y += S[n] * Cv[n];
                G[n] += zw * Pn * Cv[n];
                dA *= E;
                Pn *= Pa;
            }
            ysum0 += zw * y;
        }
        long ob = (long)(b * NC2 + c) * 5 * 192 + e;
        float P1 = Pa, P2 = P1 * Pa, P3 = P2 * Pa, P4 = P3 * Pa, P5 = P4 * Pa, P6 = P5 * Pa;
        float4 q0, q1, q2, q3, q4;
        q0.x=P1; q0.y=P2; q0.z=P3; q0.w=P4;
        q1.x=P5; q1.y=P6; q1.z=S[0]; q1.w=S[1];
        q2.x=S[2]; q2.y=S[3]; q2.z=S[4]; q2.w=S[5];
        q3.x=G[0]; q3.y=G[1]; q3.z=G[2]; q3.w=G[3];
        q4.x=G[4]; q4.y=G[5]; q4.z=ysum0; q4.w=0.0f;
        out4[ob          ] = q0;
        out4[ob + 192    ] = q1;
        out4[ob + 2 * 192] = q2;
        out4[ob + 3 * 192] = q3;
        out4[ob + 4 * 192] = q4;
    } else {
        // generic path
        float P[D_STATE];
#pragma unroll
        for (int n = 0; n < D_STATE; n++) P[n] = 1.0f;
#pragma unroll 2
        for (int t = 0; t < CT2; t++) {
            const float4* m4 = (const float4*)&sMeta[t][0];
            float4 m0 = m4[0], m1 = m4[1], mB0 = m4[2], mB1 = m4[3], mC = m4[4];
            float Bv[6] = {mB0.x, mB0.y, mB0.z, mB0.w, mB1.x, mB1.y};
            float Cv[6] = {mB1.z, mB1.w, mC.x, mC.y, mC.z, mC.w};
            float dr = dtb + m0.x * dtw[0] + m0.y * dtw[1] + m0.z * dtw[2]
                     + m0.w * dtw[3] + m1.x * dtw[4] + m1.y * dtw[5];
            float dl = softplus_fast(dr);
            float xv = bf2f(sxc[t * SXSTR + e]);
            float zw = silu_fast(zv[t]);
            float dx = dl * xv;
            float y = Dv * xv;
#pragma unroll
            for (int n = 0; n < D_STATE; n++) {
                float dA = __expf(dl * a[n]);
                S[n] = dA * S[n] + dx * Bv[n];
                P[n] *= dA;
                y += S[n] * Cv[n];
                G[n] += zw * P[n] * Cv[n];
            }
            ysum0 += zw * y;
        }
        long ob = (long)(b * NC2 + c) * 5 * 192 + e;
        float4 q0, q1, q2, q3, q4;
        q0.x=P[0]; q0.y=P[1]; q0.z=P[2]; q0.w=P[3];
        q1.x=P[4]; q1.y=P[5]; q1.z=S[0]; q1.w=S[1];
        q2.x=S[2]; q2.y=S[3]; q2.z=S[4]; q2.w=S[5];
        q3.x=G[0]; q3.y=G[1]; q3.z=G[2]; q3.w=G[3];
        q4.x=G[4]; q4.y=G[5]; q4.z=ysum0; q4.w=0.0f;
        out4[ob          ] = q0;
        out4[ob + 192    ] = q1;
        out4[ob + 2 * 192] = q2;
        out4[ob + 3 * 192] = q3;
        out4[ob + 4 * 192] = q4;
    }
}

// ---------------------------------------------------------------------------
// K4S: level-1 fold — compose CPS=8 chunks into one segment.
// ---------------------------------------------------------------------------
__global__ __launch_bounds__(192) void k4_seg(
    const float4* __restrict__ out4, float4* __restrict__ seg4)
{
    const int e = threadIdx.x;
    const int s = blockIdx.x & (NSEG - 1);
    const int b = blockIdx.x >> 4;

    float H[D_STATE], Gq[D_STATE], Pp[D_STATE];
#pragma unroll
    for (int n = 0; n < D_STATE; n++) { H[n] = 0.0f; Gq[n] = 0.0f; Pp[n] = 1.0f; }
    float yb = 0.0f;
#pragma unroll 2
    for (int cc = 0; cc < CPS; cc++) {
        int c = s * CPS + cc;
        long ob = (long)(b * NC2 + c) * 5 * 192 + e;
        float4 q0 = out4[ob];
        float4 q1 = out4[ob + 192];
        float4 q2 = out4[ob + 2 * 192];
        float4 q3 = out4[ob + 3 * 192];
        float4 q4 = out4[ob + 4 * 192];
        float Pv[6] = {q0.x, q0.y, q0.z, q0.w, q1.x, q1.y};
        float Sv[6] = {q1.z, q1.w, q2.x, q2.y, q2.z, q2.w};
        float Gv[6] = {q3.x, q3.y, q3.z, q3.w, q4.x, q4.y};
        float g = 0.0f;
#pragma unroll
        for (int n = 0; n < D_STATE; n++) g += Gv[n] * H[n];
        yb += q4.z + g;
#pragma unroll
        for (int n = 0; n < D_STATE; n++) {
            Gq[n] += Gv[n] * Pp[n];
            H[n] = Pv[n] * H[n] + Sv[n];
            Pp[n] *= Pv[n];
        }
    }
    long sb = (long)(b * NSEG + s) * 5 * 192 + e;
    float4 q0, q1, q2, q3, q4;
    q0.x=Pp[0]; q0.y=Pp[1]; q0.z=Pp[2]; q0.w=Pp[3];
    q1.x=Pp[4]; q1.y=Pp[5]; q1.z=H[0]; q1.w=H[1];
    q2.x=H[2]; q2.y=H[3]; q2.z=H[4]; q2.w=H[5];
    q3.x=Gq[0]; q3.y=Gq[1]; q3.z=Gq[2]; q3.w=Gq[3];
    q4.x=Gq[4]; q4.y=Gq[5]; q4.z=yb; q4.w=0.0f;
    seg4[sb          ] = q0;
    seg4[sb + 192    ] = q1;
    seg4[sb + 2 * 192] = q2;
    seg4[sb + 3 * 192] = q3;
    seg4[sb + 4 * 192] = q4;
}

// ---------------------------------------------------------------------------
// K4H: per-batch block: fold NSEG=16 segments -> ybar; fold 64 xbar
// partials; then output head.
// ---------------------------------------------------------------------------
__global__ __launch_bounds__(192) void k4_head(
    const float4* __restrict__ seg4, const float* __restrict__ xpart,
    const float* __restrict__ Wout,
    const float* __restrict__ fc_w, const float* __restrict__ fc_b,
    const float* __restrict__ mu_w, const float* __restrict__ mu_b,
    const float* __restrict__ sg_w, const float* __restrict__ sg_b,
    float* __restrict__ out)
{
    __shared__ float ybar[D_INNER];
    __shared__ float sxb[D_MODEL];
    __shared__ float evec[D_MODEL];
    __shared__ float feat_s[64];
    const int e = threadIdx.x;
    const int b = blockIdx.x;

    float H[D_STATE];
#pragma unroll
    for (int n = 0; n < D_STATE; n++) H[n] = 0.0f;
    float yb = 0.0f;
#pragma unroll 4
    for (int s = 0; s < NSEG; s++) {
        long ob = (long)(b * NSEG + s) * 5 * 192 + e;
        float4 q0 = seg4[ob];
        float4 q1 = seg4[ob + 192];
        float4 q2 = seg4[ob + 2 * 192];
        float4 q3 = seg4[ob + 3 * 192];
        float4 q4 = seg4[ob + 4 * 192];
        float Pv[6] = {q0.x, q0.y, q0.z, q0.w, q1.x, q1.y};
        float Sv[6] = {q1.z, q1.w, q2.x, q2.y, q2.z, q2.w};
        float Gv[6] = {q3.x, q3.y, q3.z, q3.w, q4.x, q4.y};
        float g = 0.0f;
#pragma unroll
        for (int n = 0; n < D_STATE; n++) g += Gv[n] * H[n];
        yb += q4.z + g;
#pragma unroll
        for (int n = 0; n < D_STATE; n++) H[n] = Pv[n] * H[n] + Sv[n];
    }
    ybar[e] = yb;

    // fold the 64 per-tile xbar partials for this batch
    if (e < D_MODEL) {
        const float* xp = &xpart[(long)b * 64 * 96 + e];
        float s = 0.0f;
        for (int t = 0; t < 64; t++) s += xp[t * 96];
        sxb[e] = s;
    }
    __syncthreads();

    if (e < D_MODEL) {
        float s = sxb[e];
        const float* wrow = &Wout[e * D_INNER];
        for (int e2 = 0; e2 < D_INNER; e2++) s += ybar[e2] * wrow[e2];
        evec[e] = s / (float)SEQLEN;
    }
    __syncthreads();

    if (e < 64) {
        float s = fc_b[e];
        const float* wrow = &fc_w[e * D_MODEL];
        for (int d = 0; d < D_MODEL; d++) s += evec[d] * wrow[d];
        float f = eluf(tanhf(s));
        feat_s[e] = f;
        out[b * 64 + e] = f; // feat
    }
    __syncthreads();

    if (e < 64) {
        float smu = mu_b[e], ssg = sg_b[e];
        const float* mrow = &mu_w[e * 64];
        const float* srow = &sg_w[e * 64];
        for (int i = 0; i < 64; i++) {
            smu += feat_s[i] * mrow[i];
            ssg += feat_s[i] * srow[i];
        }
        out[1024 + b * 64 + e] = smu;                        // mu
        out[2048 + b * 64 + e] = eluf(ssg) + 1.0f + 1e-14f;  // sigma
    }
}

extern "C" void kernel_launch(void* const* d_in, const int* in_sizes, int n_in,
                              void* d_out, int out_size, void* d_ws, size_t ws_size,
                              hipStream_t stream) {
    const float* x         = (const float*)d_in[0];
    const float* in_proj_w = (const float*)d_in[1];
    const float* conv_w    = (const float*)d_in[2];
    const float* conv_b    = (const float*)d_in[3];
    const float* x_proj_w  = (const float*)d_in[4];
    const float* dt_proj_w = (const float*)d_in[5];
    const float* dt_proj_b = (const float*)d_in[6];
    const float* A_log     = (const float*)d_in[7];
    const float* D_param   = (const float*)d_in[8];
    const float* out_proj_w= (const float*)d_in[9];
    const float* norm_w    = (const float*)d_in[10];
    const float* out_fc_w  = (const float*)d_in[11];
    const float* out_fc_b  = (const float*)d_in[12];
    const float* mu_w      = (const float*)d_in[13];
    const float* mu_b      = (const float*)d_in[14];
    const float* sigma_w   = (const float*)d_in[15];
    const float* sigma_b   = (const float*)d_in[16];
    float* ws = (float*)d_ws;
    float* out = (float*)d_out;

    k1_rmsnorm_inproj<<<NPOS / TP1, 256, 0, stream>>>(
        x, in_proj_w, norm_w,
        (unsigned short*)(ws + OFF_XS), (unsigned short*)(ws + OFF_Z),
        ws + OFF_XPART);

    k2f_conv_scan<<<BATCH * NC2, 192, 0, stream>>>(
        (const unsigned short*)(ws + OFF_XS), (const unsigned short*)(ws + OFF_Z),
        conv_w, conv_b, x_proj_w,
        dt_proj_w, dt_proj_b, A_log, D_param,
        (float4*)(ws + OFF_OUT4));

    k4_seg<<<BATCH * NSEG, 192, 0, stream>>>(
        (const float4*)(ws + OFF_OUT4), (float4*)(ws + OFF_SEG));

    k4_head<<<BATCH, 192, 0, stream>>>(
        (const float4*)(ws + OFF_SEG), ws + OFF_XPART, out_proj_w,
        out_fc_w, out_fc_b, mu_w, mu_b, sigma_w, sigma_b, out);
}